// Round 5
// baseline (170.660 us; speedup 1.0000x reference)
//
#include <hip/hip_runtime.h>
#include <hip/hip_cooperative_groups.h>

namespace cg = cooperative_groups;

#define NBINS 8192
#define IMG_HW 36864   // 192*192
#define NPIXBLK 144    // IMG_HW / 256
#define NINST 32
#define CCH 16
#define NH 32
#define PADW 28672     // 256*256 - 192*192
#define NB 2
#define EPSF 1e-6f
#define NACC (NINST * (CCH + 1))   // 544: 512 channel sums + 32 counts

typedef unsigned long long u64;
typedef long long i64;

// ------------------------------------------------------------------
// Workspace layout (bytes):
//   wg       : NB*NBINS*8        =  131072  (w in low32, gw in high32)
//   partials : NB*144*544*8      = 1253376  (i64 fixed-point x 2^32)
//   centers  : NB*32*16*4        =    4096
//   q        : NB*32*32*4        =    8192
//   meta     : 8*4                          [errlo, scale, maxa0, maxa1, G0, G1]
// ------------------------------------------------------------------
#define OFF_WG      0
#define OFF_PART    131072
#define OFF_CENT    1384448
#define OFF_Q       1388544
#define OFF_META    1396736

// Single cooperative kernel, 288 blocks x 256 threads, 4 phases separated by
// grid.sync() (device-scope fence => cross-XCD visibility of the globals
// written between phases). Replaces 4 separate graph nodes (launch overhead
// was ~half the total time).
__global__ void __launch_bounds__(256, 1)
k_fused(const float* __restrict__ emb, const int* __restrict__ gt,
        const float* __restrict__ W1, const float* __restrict__ b1,
        const float* __restrict__ W2, const float* __restrict__ b2,
        i64* __restrict__ partials, float* __restrict__ centers,
        float* __restrict__ q, float* __restrict__ meta,
        u64* __restrict__ wg, float* __restrict__ out) {
    cg::grid_group grid = cg::this_grid();
    int flat = blockIdx.x;
    int b = flat / NPIXBLK, blk = flat % NPIXBLK;
    int tid = threadIdx.x;

    __shared__ i64 acc[NACC];               // phase 1 partials / phase 2 sums
    __shared__ unsigned int hist[NBINS];    // phase 3 (32 KB)
    __shared__ float a_s[NINST][CCH];       // phase 2
    __shared__ float redf[4];
    __shared__ float sconst[2];
    __shared__ u64 wpart[4];                // phase 4
    __shared__ double dred[4];              // phase 4

    // ---------------- phase 1: center partial sums (+ zero wg) -------------
    for (int i = tid; i < NACC; i += 256) acc[i] = 0;
    int gid = flat * 256 + tid;
    if (gid < NB * NBINS) wg[gid] = 0ull;
    __syncthreads();

    int pix = blk * 256 + tid;
    int gtv = gt[(size_t)b * IMG_HW + pix];
    if (gtv > 0) {
        int n = gtv - 1;
        const float* e = emb + (size_t)b * CCH * IMG_HW + pix;
#pragma unroll
        for (int c = 0; c < CCH; c++) {
            i64 fx = (i64)((double)e[c * IMG_HW] * 4294967296.0);
            atomicAdd((u64*)&acc[n * CCH + c], (u64)fx);
        }
        atomicAdd((u64*)&acc[NINST * CCH + n], 1ull);
    }
    __syncthreads();
    {
        i64* pb = partials + (size_t)flat * NACC;
        for (int i = tid; i < NACC; i += 256) pb[i] = acc[i];
    }

    grid.sync();

    // ---------------- phase 2: blocks 0,1 finalize image bb ----------------
    if (flat < NB) {
        int bb = flat;
        for (int i = tid; i < NACC; i += 256) {
            i64 s = 0;
            const i64* pp = partials + (size_t)bb * NPIXBLK * NACC + i;
            for (int p = 0; p < NPIXBLK; p++) s += pp[(size_t)p * NACC];
            acc[i] = s;
        }
        __syncthreads();

        for (int i = tid; i < NINST * CCH; i += 256) {
            int n = i / CCH, c = i % CCH;
            float cntf = (float)acc[NINST * CCH + n] + EPSF;
            float raw = (float)((double)acc[i] * (1.0 / 4294967296.0));
            float a = raw / cntf * (1.f / 32.f);
            a_s[n][c] = a;
            centers[((size_t)bb * NINST + n) * CCH + c] = a;
        }
        __syncthreads();

        for (int i = tid; i < NINST * NH; i += 256) {
            int n = i / NH, j = i % NH;
            float s = b1[j];
#pragma unroll
            for (int c = 0; c < CCH; c++) s += a_s[n][c] * W1[c * NH + j];
            q[((size_t)bb * NINST + n) * NH + j] = s;
        }
        float ma = 0.f;
        for (int i = tid; i < NINST * CCH; i += 256) ma = fmaxf(ma, fabsf(a_s[i / CCH][i % CCH]));
#pragma unroll
        for (int off = 32; off > 0; off >>= 1) ma = fmaxf(ma, __shfl_down(ma, off, 64));
        if ((tid & 63) == 0) redf[tid >> 6] = ma;
        __syncthreads();
        if (tid == 0) {
            float m = fmaxf(fmaxf(redf[0], redf[1]), fmaxf(redf[2], redf[3]));
            meta[2 + bb] = m;
            float Gs = 0.f;
            for (int n = 0; n < NINST; n++) Gs += (float)acc[NINST * CCH + n];
            meta[4 + bb] = Gs;
            // conservative bound L on |logit|
            float L = fabsf(b2[0]);
            for (int j = 0; j < NH; j++) {
                float sa = 0.f;
                for (int c = 0; c < CCH; c++) sa += fabsf(W1[c * NH + j]);
                float hmax = fmaxf(b1[j] + 2.f * sa, 0.f);
                L += hmax * fabsf(W2[j]);
            }
            L += 1.f;  // margin
            float errlo = 1.f - L;
            float scale = (float)NBINS / (2.f * L);
            if (bb == 0) { meta[0] = errlo; meta[1] = scale; }
            sconst[0] = errlo;
            sconst[1] = scale;
        }
        __syncthreads();
        // padded-region items: emb=0 there, label=0, weight PADW per instance.
        if (tid < NINST) {
            int n = tid;
            float logit = b2[0];
            for (int j = 0; j < NH; j++) {
                float s = b1[j];
#pragma unroll
                for (int c = 0; c < CCH; c++) {
                    float f = fminf(fmaxf(a_s[n][c], -2.f), 2.f);
                    s += f * W1[c * NH + j];
                }
                logit += fmaxf(s, 0.f) * W2[j];
            }
            float e = 1.f + logit;  // label 0 -> sign -1
            float errlo = sconst[0], scale = sconst[1];
            int bin = (int)((e - errlo) * scale);
            bin = min(max(bin, 0), NBINS - 1);
            atomicAdd(&wg[(size_t)bb * NBINS + bin], (u64)PADW);
        }
    }

    grid.sync();

    // ---------------- phase 3: MLP + LDS histogram + flush ------------------
    for (int i = tid; i < NBINS; i += 256) hist[i] = 0u;
    __syncthreads();
    {
        const float* e = emb + (size_t)b * CCH * IMG_HW;
        float u[CCH];
        float maxu = 0.f;
#pragma unroll
        for (int c = 0; c < CCH; c++) {
            u[c] = e[c * IMG_HW + pix] * (1.f / 32.f);
            maxu = fmaxf(maxu, fabsf(u[c]));
        }
        float b2v = b2[0];
        float errlo = meta[0], scale = meta[1], maxa = meta[2 + b];
        const float* qb = q + (size_t)b * NINST * NH;
        const float* ab = centers + (size_t)b * NINST * CCH;

        if (maxu + maxa <= 2.f) {
            // no element can clip: h = relu(q_n - v), v shared across instances
            float v[NH];
#pragma unroll
            for (int j = 0; j < NH; j++) {
                float s = 0.f;
#pragma unroll
                for (int c = 0; c < CCH; c++) s += u[c] * W1[c * NH + j];
                v[j] = s;
            }
            for (int n = 0; n < NINST; n++) {
                float logit = b2v;
#pragma unroll
                for (int j = 0; j < NH; j++) logit += fmaxf(qb[n * NH + j] - v[j], 0.f) * W2[j];
                unsigned int label = (gtv == n + 1) ? 1u : 0u;
                float er = label ? (1.f - logit) : (1.f + logit);
                int bin = (int)((er - errlo) * scale);
                bin = min(max(bin, 0), NBINS - 1);
                atomicAdd(&hist[bin], 1u | (label << 16));
            }
        } else {
            // exact slow path with per-element clip
            for (int n = 0; n < NINST; n++) {
                float logit = b2v;
                for (int j = 0; j < NH; j++) {
                    float s = b1[j];
#pragma unroll
                    for (int c = 0; c < CCH; c++) {
                        float f = fminf(fmaxf(ab[n * CCH + c] - u[c], -2.f), 2.f);
                        s += f * W1[c * NH + j];
                    }
                    logit += fmaxf(s, 0.f) * W2[j];
                }
                unsigned int label = (gtv == n + 1) ? 1u : 0u;
                float er = label ? (1.f - logit) : (1.f + logit);
                int bin = (int)((er - errlo) * scale);
                bin = min(max(bin, 0), NBINS - 1);
                atomicAdd(&hist[bin], 1u | (label << 16));
            }
        }
    }
    __syncthreads();
    {
        u64* wgb = wg + (size_t)b * NBINS;
        for (int i = tid; i < NBINS; i += 256) {
            unsigned int h = hist[i];
            if (h) atomicAdd(&wgb[i], (u64)(h & 0xffffu) | ((u64)(h >> 16) << 32));
        }
    }

    grid.sync();

    // ---------------- phase 4: block 0 scans both images -------------------
    if (flat == 0) {
        const int BPT = NBINS / 256;  // 32 bins per thread
        double total = 0.0;
        for (int bb = 0; bb < NB; bb++) {
            const u64* wgb = wg + (size_t)bb * NBINS;
            double G = (double)meta[4 + bb];
            double errlo = (double)meta[0];
            double invscale = 1.0 / (double)meta[1];

            u64 tot = 0;
            for (int k = 0; k < BPT; k++) {
                int bin = NBINS - 1 - (tid * BPT + k);
                tot += wgb[bin];
            }
            u64 incl = tot;
            int lane = tid & 63, wid = tid >> 6;
#pragma unroll
            for (int off = 1; off < 64; off <<= 1) {
                u64 x = __shfl_up(incl, off, 64);
                if (lane >= off) incl += x;
            }
            if (lane == 63) wpart[wid] = incl;
            __syncthreads();
            u64 woff = 0;
            for (int w = 0; w < wid; w++) woff += wpart[w];
            u64 excl = woff + incl - tot;
            unsigned int p = (unsigned int)(excl & 0xffffffffull);
            unsigned int cs = (unsigned int)(excl >> 32);

            double loss = 0.0;
            if (G > 0.5) {
                for (int k = 0; k < BPT; k++) {
                    int bin = NBINS - 1 - (tid * BPT + k);
                    u64 v = wgb[bin];
                    unsigned int w = (unsigned int)(v & 0xffffffffull);
                    unsigned int g = (unsigned int)(v >> 32);
                    if (w) {
                        double Js = 1.0 - (G - (double)cs) / (G + (double)p - (double)cs);
                        unsigned int pe = p + w, ce = cs + g;
                        double Je = 1.0 - (G - (double)ce) / (G + (double)pe - (double)ce);
                        double rep = errlo + ((double)bin + 0.5) * invscale;
                        if (rep < 0.0) rep = 0.0;
                        loss += rep * (Je - Js);
                        p = pe;
                        cs = ce;
                    }
                }
            }
#pragma unroll
            for (int off = 32; off > 0; off >>= 1) loss += __shfl_down(loss, off, 64);
            if (lane == 0) dred[wid] = loss;
            __syncthreads();
            if (tid == 0) {
                total += dred[0] + dred[1] + dred[2] + dred[3];
            }
            __syncthreads();   // before wpart/dred reuse for next image
        }
        if (tid == 0) out[0] = (float)(total * 0.5);  // mean over 2 images
    }
}

extern "C" void kernel_launch(void* const* d_in, const int* in_sizes, int n_in,
                              void* d_out, int out_size, void* d_ws, size_t ws_size,
                              hipStream_t stream) {
    const float* emb = (const float*)d_in[0];
    const int* gt = (const int*)d_in[1];
    const float* W1 = (const float*)d_in[2];
    const float* b1 = (const float*)d_in[3];
    const float* W2 = (const float*)d_in[4];
    const float* b2 = (const float*)d_in[5];
    float* out = (float*)d_out;
    char* ws = (char*)d_ws;

    u64* wg = (u64*)(ws + OFF_WG);
    i64* partials = (i64*)(ws + OFF_PART);
    float* centers = (float*)(ws + OFF_CENT);
    float* q = (float*)(ws + OFF_Q);
    float* meta = (float*)(ws + OFF_META);

    void* args[] = {(void*)&emb, (void*)&gt, (void*)&W1, (void*)&b1,
                    (void*)&W2, (void*)&b2, (void*)&partials, (void*)&centers,
                    (void*)&q, (void*)&meta, (void*)&wg, (void*)&out};
    hipLaunchCooperativeKernel((const void*)k_fused, dim3(NB * NPIXBLK), dim3(256),
                               args, 0, stream);
}

// Round 6
// 80.933 us; speedup vs baseline: 2.1087x; 2.1087x over previous
//
#include <hip/hip_runtime.h>

#define NBINS 8192
#define IMG_HW 36864      // 192*192
#define KA_THREADS 1024
#define KA_BLKPI 36       // kA blocks per image (36*1024 = IMG_HW)
#define KB_BLKPI 144      // kB blocks per image (144*256 = IMG_HW)
#define NINST 32
#define CCH 16
#define NH 32
#define PADW 28672        // 256*256 - 192*192
#define NB 2
#define EPSF 1e-6f
#define NACC (NINST * (CCH + 1))   // 544: 512 channel sums + 32 counts

typedef unsigned long long u64;
typedef long long i64;

// ------------------------------------------------------------------
// Workspace layout (bytes):
//   wg       : NB*NBINS*8     = 131072  (w in low32, gw in high32)
//   partials : 72*544*8       = 313344  (i64 fixed-point x 2^32)
//   ticket   : 4
// ------------------------------------------------------------------
#define OFF_WG   0
#define OFF_PART 131072
#define OFF_TKT  444416

// kA: per-block center partial sums (i64 fixed-point => order-invariant,
// bit-deterministic). Also zeroes wg and the ticket counter (ws is poisoned
// 0xAA before timing, and replays must start from 0).
__global__ void __launch_bounds__(KA_THREADS)
k_centers(const float* __restrict__ emb, const int* __restrict__ gt,
          i64* __restrict__ partials, u64* __restrict__ wg,
          unsigned int* __restrict__ ticket) {
    int flat = blockIdx.x;
    int b = flat / KA_BLKPI, blk = flat % KA_BLKPI;
    int tid = threadIdx.x;
    __shared__ i64 acc[NACC];
    for (int i = tid; i < NACC; i += KA_THREADS) acc[i] = 0;
    int gid = flat * KA_THREADS + tid;
    if (gid < NB * NBINS) wg[gid] = 0ull;
    if (gid == 0) *ticket = 0u;
    __syncthreads();

    int pix = blk * KA_THREADS + tid;
    int gtv = gt[(size_t)b * IMG_HW + pix];
    if (gtv > 0) {
        int n = gtv - 1;
        const float* e = emb + (size_t)b * CCH * IMG_HW + pix;
#pragma unroll
        for (int c = 0; c < CCH; c++) {
            i64 fx = (i64)((double)e[c * IMG_HW] * 4294967296.0);
            atomicAdd((u64*)&acc[n * CCH + c], (u64)fx);
        }
        atomicAdd((u64*)&acc[NINST * CCH + n], 1ull);
    }
    __syncthreads();
    i64* pb = partials + (size_t)flat * NACC;
    for (int i = tid; i < NACC; i += KA_THREADS) pb[i] = acc[i];
}

// kB: per-block redundant finalize (partials are stream-order visible) ->
// a_s/q_s/meta in LDS; MLP + LDS histogram + flush; last-block ticket does
// the descending-bin Jaccard scan and writes out.
__global__ void __launch_bounds__(256)
k_main(const float* __restrict__ emb, const int* __restrict__ gt,
       const float* __restrict__ W1, const float* __restrict__ b1,
       const float* __restrict__ W2, const float* __restrict__ b2,
       const i64* __restrict__ partials, u64* __restrict__ wg,
       unsigned int* __restrict__ ticket, float* __restrict__ out) {
    int flat = blockIdx.x;
    int b = flat / KB_BLKPI, blk = flat % KB_BLKPI;
    int tid = threadIdx.x;

    __shared__ i64 accs[NACC];
    __shared__ unsigned int hist[NBINS];      // 32 KB
    __shared__ float a_s[NINST][CCH];
    __shared__ float q_s[NINST][NH];
    __shared__ float W2s[NH];
    __shared__ float redf[4];
    __shared__ float sLs;

    // ---- finalize (each block, redundantly, for its own image) ----
    for (int i = tid; i < NACC; i += 256) {
        i64 s = 0;
        const i64* pp = partials + ((size_t)b * KA_BLKPI) * NACC + i;
        for (int p = 0; p < KA_BLKPI; p++) s += pp[(size_t)p * NACC];
        accs[i] = s;
    }
    for (int i = tid; i < NBINS; i += 256) hist[i] = 0u;
    if (tid < NH) W2s[tid] = W2[tid];
    if (tid < 64) {
        float term = 0.f;
        if (tid < NH) {
            float sa = 0.f;
            for (int c = 0; c < CCH; c++) sa += fabsf(W1[c * NH + tid]);
            term = fmaxf(b1[tid] + 2.f * sa, 0.f) * fabsf(W2[tid]);
        }
#pragma unroll
        for (int off = 16; off > 0; off >>= 1) term += __shfl_down(term, off, 64);
        if (tid == 0) sLs = term;
    }
    __syncthreads();

    for (int i = tid; i < NINST * CCH; i += 256) {
        int n = i / CCH, c = i % CCH;
        float cntf = (float)accs[NINST * CCH + n] + EPSF;
        float a = (float)((double)accs[i] * (1.0 / 4294967296.0)) / cntf * (1.f / 32.f);
        a_s[n][c] = a;
    }
    __syncthreads();
    for (int i = tid; i < NINST * NH; i += 256) {
        int n = i / NH, j = i % NH;
        float s = b1[j];
#pragma unroll
        for (int c = 0; c < CCH; c++) s += a_s[n][c] * W1[c * NH + j];
        q_s[n][j] = s;
    }
    float ma = 0.f;
    for (int i = tid; i < NINST * CCH; i += 256) ma = fmaxf(ma, fabsf(a_s[i / CCH][i % CCH]));
#pragma unroll
    for (int off = 32; off > 0; off >>= 1) ma = fmaxf(ma, __shfl_down(ma, off, 64));
    if ((tid & 63) == 0) redf[tid >> 6] = ma;
    __syncthreads();
    float maxa = fmaxf(fmaxf(redf[0], redf[1]), fmaxf(redf[2], redf[3]));
    float b2v = b2[0];
    float L = fabsf(b2v) + sLs + 1.f;          // conservative |logit| bound + margin
    float errlo = 1.f - L;
    float scale = (float)NBINS / (2.f * L);

    // ---- padded-region items: once per image (blk==0), emb=0, label=0 ----
    if (blk == 0 && tid < NINST) {
        int n = tid;
        float logit = b2v;
        for (int j = 0; j < NH; j++) {
            float s = b1[j];
#pragma unroll
            for (int c = 0; c < CCH; c++)
                s += fminf(fmaxf(a_s[n][c], -2.f), 2.f) * W1[c * NH + j];
            logit += fmaxf(s, 0.f) * W2s[j];
        }
        float er = 1.f + logit;
        int bin = min(max((int)((er - errlo) * scale), 0), NBINS - 1);
        atomicAdd(&wg[(size_t)b * NBINS + bin], (u64)PADW);
    }

    // ---- MLP + LDS histogram ----
    int pix = blk * 256 + tid;
    int gtv = gt[(size_t)b * IMG_HW + pix];
    {
        const float* e = emb + (size_t)b * CCH * IMG_HW;
        float u[CCH];
        float maxu = 0.f;
#pragma unroll
        for (int c = 0; c < CCH; c++) {
            u[c] = e[c * IMG_HW + pix] * (1.f / 32.f);
            maxu = fmaxf(maxu, fabsf(u[c]));
        }
        if (maxu + maxa <= 2.f) {
            // no element can clip: h = relu(q_n - v), v shared across instances
            float v[NH];
#pragma unroll
            for (int j = 0; j < NH; j++) {
                float s = 0.f;
#pragma unroll
                for (int c = 0; c < CCH; c++) s += u[c] * W1[c * NH + j];
                v[j] = s;
            }
            for (int n = 0; n < NINST; n++) {
                float logit = b2v;
#pragma unroll
                for (int j = 0; j < NH; j++)
                    logit += fmaxf(q_s[n][j] - v[j], 0.f) * W2s[j];
                unsigned int label = (gtv == n + 1) ? 1u : 0u;
                float er = label ? (1.f - logit) : (1.f + logit);
                int bin = min(max((int)((er - errlo) * scale), 0), NBINS - 1);
                atomicAdd(&hist[bin], 1u | (label << 16));
            }
        } else {
            // exact slow path with per-element clip
            for (int n = 0; n < NINST; n++) {
                float logit = b2v;
                for (int j = 0; j < NH; j++) {
                    float s = b1[j];
#pragma unroll
                    for (int c = 0; c < CCH; c++) {
                        float f = fminf(fmaxf(a_s[n][c] - u[c], -2.f), 2.f);
                        s += f * W1[c * NH + j];
                    }
                    logit += fmaxf(s, 0.f) * W2s[j];
                }
                unsigned int label = (gtv == n + 1) ? 1u : 0u;
                float er = label ? (1.f - logit) : (1.f + logit);
                int bin = min(max((int)((er - errlo) * scale), 0), NBINS - 1);
                atomicAdd(&hist[bin], 1u | (label << 16));
            }
        }
    }
    __syncthreads();
    {
        u64* wgb = wg + (size_t)b * NBINS;
        for (int i = tid; i < NBINS; i += 256) {
            unsigned int h = hist[i];
            if (h) atomicAdd(&wgb[i], (u64)(h & 0xffffu) | ((u64)(h >> 16) << 32));
        }
    }

    // ---- last-block ticket (deadlock-free: losers exit) ----
    __threadfence();
    __syncthreads();
    __shared__ unsigned int stk;
    if (tid == 0)
        stk = __hip_atomic_fetch_add(ticket, 1u, __ATOMIC_ACQ_REL,
                                     __HIP_MEMORY_SCOPE_AGENT);
    __syncthreads();
    if (stk != (unsigned)(NB * KB_BLKPI - 1)) return;

    // ---- winner: G per image from partials (stream-visible, exact ints) ----
    __shared__ float sG[NB];
    if (tid < 64) {
        int bb = tid >> 5, n = tid & 31;
        i64 g = 0;
        const i64* pp = partials + ((size_t)bb * KA_BLKPI) * NACC + NINST * CCH + n;
        for (int p = 0; p < KA_BLKPI; p++) g += pp[(size_t)p * NACC];
#pragma unroll
        for (int off = 16; off > 0; off >>= 1) g += __shfl_down(g, off, 32);
        if (n == 0) sG[bb] = (float)g;
    }
    __syncthreads();

    // ---- winner: descending-bin Jaccard scan (device-scope loads) ----
    __shared__ u64 wpart[4];
    __shared__ double dred[4];
    const int BPT = NBINS / 256;   // 32 bins per thread
    double total = 0.0;
    int lane = tid & 63, wid = tid >> 6;
    for (int bb = 0; bb < NB; bb++) {
        const u64* wgs = wg + (size_t)bb * NBINS;
        double G = (double)sG[bb];
        double delo = (double)errlo;
        double invscale = 1.0 / (double)scale;

        u64 tot = 0;
        for (int k = 0; k < BPT; k++) {
            int bin = NBINS - 1 - (tid * BPT + k);
            tot += __hip_atomic_load(&wgs[bin], __ATOMIC_RELAXED,
                                     __HIP_MEMORY_SCOPE_AGENT);
        }
        u64 incl = tot;
#pragma unroll
        for (int off = 1; off < 64; off <<= 1) {
            u64 x = __shfl_up(incl, off, 64);
            if (lane >= off) incl += x;
        }
        if (lane == 63) wpart[wid] = incl;
        __syncthreads();
        u64 woff = 0;
        for (int w = 0; w < wid; w++) woff += wpart[w];
        u64 excl = woff + incl - tot;
        unsigned int p = (unsigned int)(excl & 0xffffffffull);
        unsigned int cs = (unsigned int)(excl >> 32);

        double loss = 0.0;
        if (G > 0.5) {
            for (int k = 0; k < BPT; k++) {
                int bin = NBINS - 1 - (tid * BPT + k);
                u64 v = __hip_atomic_load(&wgs[bin], __ATOMIC_RELAXED,
                                          __HIP_MEMORY_SCOPE_AGENT);
                unsigned int w = (unsigned int)(v & 0xffffffffull);
                unsigned int g = (unsigned int)(v >> 32);
                if (w) {
                    double Js = 1.0 - (G - (double)cs) / (G + (double)p - (double)cs);
                    unsigned int pe = p + w, ce = cs + g;
                    double Je = 1.0 - (G - (double)ce) / (G + (double)pe - (double)ce);
                    double rep = delo + ((double)bin + 0.5) * invscale;
                    if (rep < 0.0) rep = 0.0;
                    loss += rep * (Je - Js);
                    p = pe;
                    cs = ce;
                }
            }
        }
#pragma unroll
        for (int off = 32; off > 0; off >>= 1) loss += __shfl_down(loss, off, 64);
        if (lane == 0) dred[wid] = loss;
        __syncthreads();
        if (tid == 0) total += dred[0] + dred[1] + dred[2] + dred[3];
        __syncthreads();   // before wpart/dred reuse
    }
    if (tid == 0) out[0] = (float)(total * 0.5);  // mean over 2 images
}

extern "C" void kernel_launch(void* const* d_in, const int* in_sizes, int n_in,
                              void* d_out, int out_size, void* d_ws, size_t ws_size,
                              hipStream_t stream) {
    const float* emb = (const float*)d_in[0];
    const int* gt = (const int*)d_in[1];
    const float* W1 = (const float*)d_in[2];
    const float* b1 = (const float*)d_in[3];
    const float* W2 = (const float*)d_in[4];
    const float* b2 = (const float*)d_in[5];
    float* out = (float*)d_out;
    char* ws = (char*)d_ws;

    u64* wg = (u64*)(ws + OFF_WG);
    i64* partials = (i64*)(ws + OFF_PART);
    unsigned int* ticket = (unsigned int*)(ws + OFF_TKT);

    k_centers<<<dim3(NB * KA_BLKPI), KA_THREADS, 0, stream>>>(emb, gt, partials, wg, ticket);
    k_main<<<dim3(NB * KB_BLKPI), 256, 0, stream>>>(emb, gt, W1, b1, W2, b2,
                                                    partials, wg, ticket, out);
}